// Round 1
// baseline (122.460 us; speedup 1.0000x reference)
//
#include <hip/hip_runtime.h>
#include <hip/hip_bf16.h>

// MeanAggregator: out[n, :] = mean_{s<12} feature[idx[n,s], :]
// feature: [200000, 64] f32, idx: [100000, 12] int, out: [100000, 64] f32
//
// Layout: 16 lanes per node, each lane owns one float4 (16B) of the 256B row.
// One wave = 4 nodes; each gather load instruction moves 4 rows x 256B = 1KB.
// Sample loop fully unrolled -> 12 independent loads in flight per thread.

#define N_NODES  100000
#define N_SAMPLE 12
#define D_FEAT   64
#define LANES_PER_NODE 16   // D_FEAT/4 floats per float4

__global__ __launch_bounds__(256) void mean_agg_kernel(
    const float4* __restrict__ feat4,   // [N_TOTAL, 16] as float4
    const int*    __restrict__ idx,     // [N_NODES, N_SAMPLE]
    float4*       __restrict__ out4)    // [N_NODES, 16] as float4
{
    const int t    = blockIdx.x * blockDim.x + threadIdx.x;
    const int node = t >> 4;          // /16
    const int c    = t & 15;          // float4 slot within the row
    if (node >= N_NODES) return;

    const int* nidx = idx + node * N_SAMPLE;

    // Load all 12 indices first (broadcast across the 16 lanes of this node),
    // then issue 12 independent row-gather loads.
    int j[N_SAMPLE];
#pragma unroll
    for (int s = 0; s < N_SAMPLE; ++s) j[s] = nidx[s];

    float4 acc = make_float4(0.f, 0.f, 0.f, 0.f);
#pragma unroll
    for (int s = 0; s < N_SAMPLE; ++s) {
        float4 v = feat4[(size_t)j[s] * LANES_PER_NODE + c];
        acc.x += v.x; acc.y += v.y; acc.z += v.z; acc.w += v.w;
    }

    const float inv = 1.0f / (float)N_SAMPLE;
    acc.x *= inv; acc.y *= inv; acc.z *= inv; acc.w *= inv;
    out4[t] = acc;
}

extern "C" void kernel_launch(void* const* d_in, const int* in_sizes, int n_in,
                              void* d_out, int out_size, void* d_ws, size_t ws_size,
                              hipStream_t stream) {
    const float4* feat4 = (const float4*)d_in[0];
    const int*    idx   = (const int*)d_in[1];
    float4*       out4  = (float4*)d_out;

    const int total_threads = N_NODES * LANES_PER_NODE;   // 1.6M
    const int block = 256;
    const int grid  = (total_threads + block - 1) / block; // 6250

    mean_agg_kernel<<<grid, block, 0, stream>>>(feat4, idx, out4);
}